// Round 15
// baseline (411.694 us; speedup 1.0000x reference)
//
#include <hip/hip_runtime.h>

// ---------------------------------------------------------------------------
// SchNet-style GNN on MI355X — R15.
// R15 = R14 with k_edge restructured: each wave processes 64 sorted edges in
// 4 rounds of 16, carrying the segmented accumulator (cur,a) across rounds
// in registers -> ~3x fewer global atomic flushes (run length ~32 spans
// rounds instead of being cut at 16). Wave-private LDS M tile reused per
// round (program order, no barriers). k_s1 frozen per R12-R14 stop rule.
// ---------------------------------------------------------------------------

typedef short bf16x8 __attribute__((ext_vector_type(8)));
typedef unsigned short ushort8 __attribute__((ext_vector_type(8)));
typedef float floatx4 __attribute__((ext_vector_type(4)));

#define HCH 128
#define FCH 64
#define GCH 50
#define LN  3
#define TBL 4096
#define CAP1 6144        // slots per 128-node coarse bucket (mean 4096)
#define CHUNK 1024       // edges per k_s1 block
#define DMAX 8.6603f     // pos in [0,5)^3 -> d <= 5*sqrt(3)

#define MFMA(a, b, c) __builtin_amdgcn_mfma_f32_16x16x32_bf16((a), (b), (c), 0, 0, 0)

__device__ __forceinline__ unsigned short f2bf(float x) {
    unsigned int u = __float_as_uint(x);
    unsigned int r = (u + 0x7FFFu + ((u >> 16) & 1u)) >> 16;
    return (unsigned short)r;
}

__device__ __forceinline__ unsigned pk2bf(float lo, float hi) {
    unsigned ulo = __float_as_uint(lo) + 0x8000u;
    unsigned uhi = __float_as_uint(hi) + 0x8000u;
    return __builtin_amdgcn_perm(uhi, ulo, 0x07060302u);
}

__device__ __forceinline__ float bf2f(unsigned short u) {
    return __uint_as_float((unsigned)u << 16);
}

__device__ __forceinline__ float sspf(float x) {
    float t = __expf(-fabsf(x));
    float l = __logf(1.f + t);
    return fmaxf(x, 0.f) + l - 0.69314718056f;
}

// ---------------------------------------------------------------------------
// frag fill for node-side MFMA weights (B-fragment order)
// ---------------------------------------------------------------------------
__device__ __forceinline__ void fill_frag(const float* __restrict__ src,
                                          short* __restrict__ dst,
                                          int K, int F, int Ksrc,
                                          int tid, int nthr)
{
    int kc = K >> 5;
    int total = (F >> 4) * kc * 512;
    for (int i = tid; i < total; i += nthr) {
        int j = i & 7;
        int lane = (i >> 3) & 63;
        int rest = i >> 9;
        int kk = rest % kc;
        int nt = rest / kc;
        int k = kk * 32 + ((lane >> 4) << 3) + j;
        int f = nt * 16 + (lane & 15);
        float v = (k < Ksrc) ? src[k * F + f] : 0.f;
        dst[i] = (short)f2bf(v);
    }
}

__global__ void k_prep(const float* __restrict__ l1w, const float* __restrict__ l2w,
                       const float* __restrict__ lw,  const float* __restrict__ ow1,
                       short* __restrict__ l1wp, short* __restrict__ l2wp,
                       short* __restrict__ lwp,  short* __restrict__ ow1p)
{
    int tid = blockIdx.x * blockDim.x + threadIdx.x;
    int nthr = gridDim.x * blockDim.x;
    for (int l = 0; l < LN; l++) {
        fill_frag(l1w + l * HCH * FCH, l1wp + l * 8192, 128, 64, 128, tid, nthr);
        fill_frag(l2w + l * FCH * HCH, l2wp + l * 8192, 64, 128, 64, tid, nthr);
        fill_frag(lw  + l * HCH * HCH, lwp  + l * 16384, 128, 128, 128, tid, nthr);
    }
    fill_frag(ow1, ow1p, 128, 64, 128, tid, nthr);
}

// ---------------------------------------------------------------------------
// Wtab[l][k][f] = (ssp(ea(d_k)@mw1+b1)@mw2+b2)[f] * C(d_k), bf16.
// ---------------------------------------------------------------------------
__global__ __launch_bounds__(64) void k_wtab(
    const float* __restrict__ mw1, const float* __restrict__ mb1,
    const float* __restrict__ mw2, const float* __restrict__ mb2,
    unsigned short* __restrict__ Wtb)
{
    __shared__ float sh[64];
    int blk = blockIdx.x;          // l*TBL + k
    int l = blk / TBL, k = blk - l * TBL;
    int f = threadIdx.x;
    float d = (float)k * (DMAX / (float)(TBL - 1));
    const float step = 10.f / 49.f;
    const float coeff = -0.5f / (step * step);

    float t1 = mb1[l * 64 + f];
    const float* w1 = mw1 + l * GCH * 64;
    for (int g = 0; g < GCH; g++) {
        float u = d - (float)g * step;
        t1 += __expf(coeff * u * u) * w1[g * 64 + f];
    }
    sh[f] = sspf(t1);              // one wave: program order suffices
    float acc = mb2[l * 64 + f];
    const float* w2 = mw2 + l * 64 * 64;
    for (int g = 0; g < 64; g++) acc += sh[g] * w2[g * 64 + f];
    float C = 0.5f * (__cosf(d * 0.31415926535897932f) + 1.f);
    Wtb[(size_t)blk * 64 + f] = f2bf(acc * C);
}

// ---------------------------------------------------------------------------
// Stage 1: coarse-bucket (dst>>7) partition of a 1024-edge chunk.
// (frozen — at its latency floor per R12-R14)
// ---------------------------------------------------------------------------
__global__ __launch_bounds__(256, 2) void k_s1(
    const int* __restrict__ ei, const float* __restrict__ pos,
    int* __restrict__ gcur, int2* __restrict__ ebuf, int E, int nb1)
{
    __shared__ int hist[512];
    __shared__ int lstart[512];
    __shared__ int lcur[512];
    __shared__ int gbase[512];
    __shared__ int wsum[4];
    __shared__ int2 stage[CHUNK];

    int t = threadIdx.x, lane = t & 63, w = t >> 6;
    int e0 = blockIdx.x * CHUNK;
    int e1 = min(e0 + CHUNK, E);
    int cnt = e1 - e0;

    for (int i = t; i < 512; i += 256) hist[i] = 0;
    __syncthreads();

    int esrc[4], edst[4];
    float psx[4], psy[4], psz[4], pdx[4], pdy[4], pdz[4];
    bool val[4];
#pragma unroll
    for (int i = 0; i < 4; i++) {
        int e = e0 + t + i * 256;
        val[i] = e < e1;
        int ec = min(e, E - 1);
        esrc[i] = ei[ec];
        edst[i] = ei[E + ec];
    }
#pragma unroll
    for (int i = 0; i < 4; i++) {
        int s = esrc[i], d2 = edst[i];
        psx[i] = pos[s * 3 + 0]; psy[i] = pos[s * 3 + 1]; psz[i] = pos[s * 3 + 2];
        pdx[i] = pos[d2 * 3 + 0]; pdy[i] = pos[d2 * 3 + 1]; pdz[i] = pos[d2 * 3 + 2];
    }
    int2 my[4];
    int  mybk[4];
#pragma unroll
    for (int i = 0; i < 4; i++) {
        float dx = psx[i] - pdx[i];
        float dy = psy[i] - pdy[i];
        float dz = psz[i] - pdz[i];
        float dist = sqrtf(dx * dx + dy * dy + dz * dz);
        int tix = (int)(dist * ((float)(TBL - 1) / DMAX) + 0.5f);
        tix = (tix > TBL - 1) ? (TBL - 1) : tix;
        my[i] = make_int2(esrc[i] | (tix << 17), edst[i]);
        mybk[i] = val[i] ? (edst[i] >> 7) : -1;
        if (mybk[i] >= 0) atomicAdd(&hist[mybk[i]], 1);
    }
    __syncthreads();

    {
        int base = w * 128;
        int c0 = hist[base + lane];
        int c1 = hist[base + 64 + lane];
        int a = c0, b = c1;
#pragma unroll
        for (int o = 1; o < 64; o <<= 1) {
            int ua = __shfl_up(a, o, 64);
            int ub = __shfl_up(b, o, 64);
            if (lane >= o) { a += ua; b += ub; }
        }
        int atot = __shfl(a, 63, 64);
        b += atot;
        if (lane == 63) wsum[w] = b;
        __syncthreads();
        int prefix = 0;
#pragma unroll
        for (int i = 0; i < 4; i++) if (i < w) prefix += wsum[i];
        int ls0 = prefix + a - c0;
        int ls1 = prefix + b - c1;
        int bk0 = base + lane, bk1 = base + 64 + lane;
        lstart[bk0] = ls0; lcur[bk0] = ls0;
        lstart[bk1] = ls1; lcur[bk1] = ls1;
        int base0 = (c0 && bk0 < nb1) ? atomicAdd(&gcur[bk0 * 16], c0) : 0;
        int base1 = (c1 && bk1 < nb1) ? atomicAdd(&gcur[bk1 * 16], c1) : 0;
        gbase[bk0] = bk0 * CAP1 + base0;
        gbase[bk1] = bk1 * CAP1 + base1;
    }
    __syncthreads();

#pragma unroll
    for (int i = 0; i < 4; i++) {
        if (mybk[i] >= 0) {
            int ofs = atomicAdd(&lcur[mybk[i]], 1);
            stage[ofs] = my[i];
        }
    }
    __syncthreads();

    for (int i = t; i < cnt; i += 256) {
        int2 ed = stage[i];
        int bk = ed.y >> 7;
        int g = gbase[bk] + (i - lstart[bk]);
        if (g < bk * CAP1 + CAP1) ebuf[g] = ed;
    }
}

// ---------------------------------------------------------------------------
// Stage 2: per-bucket LDS counting sort by dst -> dense sorted int2 edata.
// ---------------------------------------------------------------------------
__global__ __launch_bounds__(512) void k_s2(
    const int2* __restrict__ ebuf, const int* __restrict__ gcur,
    int2* __restrict__ edata, int nb1)
{
    __shared__ int hist[128];
    __shared__ int bcur[128];
    __shared__ int wred[8];
    int t = threadIdx.x, lane = t & 63, w = t >> 6, bk = blockIdx.x;
    int cnt = min(gcur[bk * 16], CAP1);

    int v = (t < bk && t < nb1) ? min(gcur[t * 16], CAP1) : 0;
#pragma unroll
    for (int o = 32; o; o >>= 1) v += __shfl_down(v, o, 64);
    if (lane == 0) wred[w] = v;
    if (t < 128) hist[t] = 0;
    __syncthreads();
    int gs = 0;
#pragma unroll
    for (int i = 0; i < 8; i++) gs += wred[i];

    const int2* eb = ebuf + (size_t)bk * CAP1;
    for (int i = t; i < cnt; i += 512)
        atomicAdd(&hist[eb[i].y & 127], 1);
    __syncthreads();
    int myc = (t < 128) ? hist[t] : 0;
    for (int o = 1; o < 128; o <<= 1) {
        int u = (t < 128 && t >= o) ? hist[t - o] : 0;
        __syncthreads();
        if (t < 128) hist[t] += u;
        __syncthreads();
    }
    if (t < 128) bcur[t] = gs + hist[t] - myc;
    __syncthreads();
    for (int i = t; i < cnt; i += 512) {
        int2 ed = eb[i];
        int dl = ed.y & 127;
        int p = atomicAdd(&bcur[dl], 1);
        edata[p] = ed;
    }
}

// ---------------------------------------------------------------------------
// k_node0: h = emb[z]; xj = h @ l1w[0] (bf16 out); agg = 0 for layer 0
// ---------------------------------------------------------------------------
__global__ __launch_bounds__(256) void k_node0(const int* __restrict__ z,
    const float* __restrict__ emb, const short* __restrict__ l1wp0,
    float* __restrict__ h, unsigned short* __restrict__ xjb,
    float* __restrict__ agg, int N)
{
    __shared__ __align__(16) short A3[8192];
    __shared__ int zL[64];
    int t = threadIdx.x, lane = t & 63, w = t >> 6;
    int n0 = blockIdx.x * 64;
    if (t < 64) { int n = n0 + t; zL[t] = (n < N) ? z[n] : 0; }
    __syncthreads();
    for (int i = t; i < 4096; i += 256) {
        int n = n0 + (i >> 6);
        if (n < N) agg[(size_t)n * FCH + (i & 63)] = 0.f;
    }
#pragma unroll
    for (int m = 0; m < 16; m++) {
        int ii = lane + 64 * m;
        int rloc = ii >> 6;
        int k0 = (ii & 63) * 2;
        int n = n0 + w * 16 + rloc;
        float2 v = make_float2(0.f, 0.f);
        if (n < N) {
            v = *(const float2*)(&emb[(size_t)zL[w * 16 + rloc] * HCH + k0]);
            *(float2*)(&h[(size_t)n * HCH + k0]) = v;
        }
        unsigned pk = pk2bf(v.x, v.y);
        int si = w * 2048 + (k0 >> 5) * 512 + (rloc + 16 * ((k0 >> 3) & 3)) * 8 + (k0 & 7);
        *(unsigned*)(&A3[si]) = pk;
    }
    int quad = lane >> 4, col = lane & 15;
    const bf16x8* B = (const bf16x8*)l1wp0;
    bf16x8 af[4];
#pragma unroll
    for (int kk = 0; kk < 4; kk++)
        af[kk] = *(const bf16x8*)(&A3[w * 2048 + kk * 512 + lane * 8]);
#pragma unroll
    for (int nt = 0; nt < 4; nt++) {
        floatx4 c = {0.f, 0.f, 0.f, 0.f};
#pragma unroll
        for (int kk = 0; kk < 4; kk++) c = MFMA(af[kk], B[(nt * 4 + kk) * 64 + lane], c);
        int f = nt * 16 + col;
#pragma unroll
        for (int reg = 0; reg < 4; reg++) {
            int n = n0 + w * 16 + quad * 4 + reg;
            if (n < N) xjb[(size_t)n * FCH + f] = f2bf(c[reg]);
        }
    }
}

// ---------------------------------------------------------------------------
// Edge kernel R15: 256 edges/block, each wave owns 64 sorted edges processed
// in 4 rounds of 16; segmented accumulator (cur,a) carried across rounds in
// registers -> ~3x fewer atomic flushes. Wave-private LDS, no barriers.
// ---------------------------------------------------------------------------
__global__ __launch_bounds__(256) void k_edge(
    const int2* __restrict__ edata, const unsigned short* __restrict__ xjb,
    const unsigned short* __restrict__ Wt, float* __restrict__ agg, int E)
{
    __shared__ float M[64 * 68];
    __shared__ int tD[64];

    int t = threadIdx.x, lane = t & 63, w = t >> 6;
    int rloc = lane >> 2;             // 0..15: local edge row in the round
    int fq = lane & 3;                // 16-float chunk
    int ebase = blockIdx.x * 256 + w * 64;
    int base = w * 16;

    float a = 0.f;
    int cur = -1;
    int f = lane;                     // reduce-phase feature

#pragma unroll
    for (int q = 0; q < 4; q++) {
        int eg = ebase + q * 16 + rloc;
        int2 ed = make_int2(0, -1);
        if (eg < E) ed = edata[eg];
        int src = ed.x & 0x1FFFF;
        int tix = ((unsigned)ed.x) >> 17;
        if (fq == 0) tD[base + rloc] = ed.y;

        const ushort8* Wr = (const ushort8*)(Wt + ((size_t)tix << 6) + fq * 16);
        const ushort8* X  = (const ushort8*)(xjb + ((size_t)src << 6) + fq * 16);
        ushort8 w0 = Wr[0];
        ushort8 w1 = Wr[1];
        ushort8 xA = X[0];
        ushort8 xB = X[1];

        float* Mr = &M[(base + rloc) * 68 + fq * 16];
        float4 m;
        m.x = bf2f(w0[0]) * bf2f(xA[0]); m.y = bf2f(w0[1]) * bf2f(xA[1]);
        m.z = bf2f(w0[2]) * bf2f(xA[2]); m.w = bf2f(w0[3]) * bf2f(xA[3]);
        *(float4*)(Mr + 0) = m;
        m.x = bf2f(w0[4]) * bf2f(xA[4]); m.y = bf2f(w0[5]) * bf2f(xA[5]);
        m.z = bf2f(w0[6]) * bf2f(xA[6]); m.w = bf2f(w0[7]) * bf2f(xA[7]);
        *(float4*)(Mr + 4) = m;
        m.x = bf2f(w1[0]) * bf2f(xB[0]); m.y = bf2f(w1[1]) * bf2f(xB[1]);
        m.z = bf2f(w1[2]) * bf2f(xB[2]); m.w = bf2f(w1[3]) * bf2f(xB[3]);
        *(float4*)(Mr + 8) = m;
        m.x = bf2f(w1[4]) * bf2f(xB[4]); m.y = bf2f(w1[5]) * bf2f(xB[5]);
        m.z = bf2f(w1[6]) * bf2f(xB[6]); m.w = bf2f(w1[7]) * bf2f(xB[7]);
        *(float4*)(Mr + 12) = m;

        // segmented reduce over this round's 16 rows (accumulator carried)
#pragma unroll
        for (int i = 0; i < 16; i++) {
            int d2 = tD[base + i];
            if (d2 != cur) {
                if (cur >= 0) unsafeAtomicAdd(&agg[(size_t)cur * FCH + f], a);
                a = 0.f; cur = d2;
            }
            a += M[(base + i) * 68 + f];
        }
    }
    if (cur >= 0) unsafeAtomicAdd(&agg[(size_t)cur * FCH + f], a);
}

// ---------------------------------------------------------------------------
// Node update (layers 0,1): single LDS arena; zeroes its agg rows for the
// next layer right after staging them.
// ---------------------------------------------------------------------------
__global__ __launch_bounds__(256) void k_update(
    float* __restrict__ agg, const short* __restrict__ l2wp,
    const float* __restrict__ l2b, const short* __restrict__ lwp,
    const float* __restrict__ lb,  const short* __restrict__ l1wp_next,
    float* __restrict__ h, unsigned short* __restrict__ xjb, int layer, int N)
{
    __shared__ __align__(16) short AR[8192];
    int t = threadIdx.x, lane = t & 63, w = t >> 6;
    int n0 = blockIdx.x * 64;
    short* WR = &AR[w * 2048];
#pragma unroll
    for (int m = 0; m < 8; m++) {
        int ii = lane + 64 * m;
        int rloc = ii >> 5;
        int k0 = (ii & 31) * 2;
        int n = n0 + w * 16 + rloc;
        float2 v = make_float2(0.f, 0.f);
        if (n < N) v = *(const float2*)(&agg[(size_t)n * FCH + k0]);
        unsigned pk = pk2bf(v.x, v.y);
        int si = (k0 >> 5) * 512 + (rloc + 16 * ((k0 >> 3) & 3)) * 8 + (k0 & 7);
        *(unsigned*)(&WR[si]) = pk;
    }
#pragma unroll
    for (int i = 0; i < 16; i++) {
        int n = n0 + w * 16 + i;
        if (n < N) agg[(size_t)n * FCH + lane] = 0.f;
    }
    int quad = lane >> 4, col = lane & 15;
    const bf16x8* Bl2 = (const bf16x8*)(l2wp + layer * 8192);
    const bf16x8* Blw = (const bf16x8*)(lwp + layer * 16384);
    const bf16x8* Bl1 = (const bf16x8*)l1wp_next;

    bf16x8 a0 = *(const bf16x8*)(&WR[lane * 8]);
    bf16x8 a1 = *(const bf16x8*)(&WR[512 + lane * 8]);
#pragma unroll
    for (int nt = 0; nt < 8; nt++) {
        float bias = l2b[layer * HCH + nt * 16 + col];
        floatx4 c = {bias, bias, bias, bias};
        c = MFMA(a0, Bl2[(nt * 2 + 0) * 64 + lane], c);
        c = MFMA(a1, Bl2[(nt * 2 + 1) * 64 + lane], c);
        int f = nt * 16 + col;
        int si0 = (f >> 5) * 512 + (16 * ((f >> 3) & 3)) * 8 + (f & 7);
#pragma unroll
        for (int reg = 0; reg < 4; reg++)
            WR[si0 + (quad * 4 + reg) * 8] = (short)f2bf(sspf(c[reg]));
    }
    bf16x8 af[4];
#pragma unroll
    for (int kk = 0; kk < 4; kk++)
        af[kk] = *(const bf16x8*)(&WR[kk * 512 + lane * 8]);
#pragma unroll
    for (int nt = 0; nt < 8; nt++) {
        float bias = lb[layer * HCH + nt * 16 + col];
        floatx4 c = {bias, bias, bias, bias};
#pragma unroll
        for (int kk = 0; kk < 4; kk++) c = MFMA(af[kk], Blw[(nt * 4 + kk) * 64 + lane], c);
        int f = nt * 16 + col;
        int si0 = (f >> 5) * 512 + (16 * ((f >> 3) & 3)) * 8 + (f & 7);
#pragma unroll
        for (int reg = 0; reg < 4; reg++) {
            int n = n0 + w * 16 + quad * 4 + reg;
            float hv = 0.f;
            if (n < N) {
                hv = h[(size_t)n * HCH + f] + c[reg];
                h[(size_t)n * HCH + f] = hv;
            }
            WR[si0 + (quad * 4 + reg) * 8] = (short)f2bf(hv);
        }
    }
#pragma unroll
    for (int kk = 0; kk < 4; kk++)
        af[kk] = *(const bf16x8*)(&WR[kk * 512 + lane * 8]);
#pragma unroll
    for (int nt = 0; nt < 4; nt++) {
        floatx4 c = {0.f, 0.f, 0.f, 0.f};
#pragma unroll
        for (int kk = 0; kk < 4; kk++) c = MFMA(af[kk], Bl1[(nt * 4 + kk) * 64 + lane], c);
        int f = nt * 16 + col;
#pragma unroll
        for (int reg = 0; reg < 4; reg++) {
            int n = n0 + w * 16 + quad * 4 + reg;
            if (n < N) xjb[(size_t)n * FCH + f] = f2bf(c[reg]);
        }
    }
}

// ---------------------------------------------------------------------------
// Final layer: node update + output MLP + segmented-shuffle readout.
// ---------------------------------------------------------------------------
__global__ __launch_bounds__(256) void k_final(
    const float* __restrict__ agg, const short* __restrict__ l2wp,
    const float* __restrict__ l2b, const short* __restrict__ lwp,
    const float* __restrict__ lb,  const short* __restrict__ ow1p,
    const float* __restrict__ ob1, const float* __restrict__ ow2,
    const float* __restrict__ ob2, const int* __restrict__ batch,
    const float* __restrict__ h, float* __restrict__ out, int layer, int N)
{
    __shared__ __align__(16) short AR[8192];
    __shared__ float R[64 * 17];
    int t = threadIdx.x, lane = t & 63, w = t >> 6;
    int n0 = blockIdx.x * 64;
    short* WR = &AR[w * 2048];
#pragma unroll
    for (int m = 0; m < 8; m++) {
        int ii = lane + 64 * m;
        int rloc = ii >> 5;
        int k0 = (ii & 31) * 2;
        int n = n0 + w * 16 + rloc;
        float2 v = make_float2(0.f, 0.f);
        if (n < N) v = *(const float2*)(&agg[(size_t)n * FCH + k0]);
        unsigned pk = pk2bf(v.x, v.y);
        int si = (k0 >> 5) * 512 + (rloc + 16 * ((k0 >> 3) & 3)) * 8 + (k0 & 7);
        *(unsigned*)(&WR[si]) = pk;
    }
    int quad = lane >> 4, col = lane & 15;
    const bf16x8* Bl2 = (const bf16x8*)(l2wp + layer * 8192);
    const bf16x8* Blw = (const bf16x8*)(lwp + layer * 16384);
    const bf16x8* Bow = (const bf16x8*)ow1p;

    bf16x8 a0 = *(const bf16x8*)(&WR[lane * 8]);
    bf16x8 a1 = *(const bf16x8*)(&WR[512 + lane * 8]);
#pragma unroll
    for (int nt = 0; nt < 8; nt++) {
        float bias = l2b[layer * HCH + nt * 16 + col];
        floatx4 c = {bias, bias, bias, bias};
        c = MFMA(a0, Bl2[(nt * 2 + 0) * 64 + lane], c);
        c = MFMA(a1, Bl2[(nt * 2 + 1) * 64 + lane], c);
        int f = nt * 16 + col;
        int si0 = (f >> 5) * 512 + (16 * ((f >> 3) & 3)) * 8 + (f & 7);
#pragma unroll
        for (int reg = 0; reg < 4; reg++)
            WR[si0 + (quad * 4 + reg) * 8] = (short)f2bf(sspf(c[reg]));
    }
    bf16x8 af[4];
#pragma unroll
    for (int kk = 0; kk < 4; kk++)
        af[kk] = *(const bf16x8*)(&WR[kk * 512 + lane * 8]);
#pragma unroll
    for (int nt = 0; nt < 8; nt++) {
        float bias = lb[layer * HCH + nt * 16 + col];
        floatx4 c = {bias, bias, bias, bias};
#pragma unroll
        for (int kk = 0; kk < 4; kk++) c = MFMA(af[kk], Blw[(nt * 4 + kk) * 64 + lane], c);
        int f = nt * 16 + col;
        int si0 = (f >> 5) * 512 + (16 * ((f >> 3) & 3)) * 8 + (f & 7);
#pragma unroll
        for (int reg = 0; reg < 4; reg++) {
            int n = n0 + w * 16 + quad * 4 + reg;
            float hv = 0.f;
            if (n < N) hv = h[(size_t)n * HCH + f] + c[reg];
            WR[si0 + (quad * 4 + reg) * 8] = (short)f2bf(hv);
        }
    }
#pragma unroll
    for (int kk = 0; kk < 4; kk++)
        af[kk] = *(const bf16x8*)(&WR[kk * 512 + lane * 8]);
    float p[4] = {0.f, 0.f, 0.f, 0.f};
#pragma unroll
    for (int nt = 0; nt < 4; nt++) {
        float bias = ob1[nt * 16 + col];
        floatx4 c = {bias, bias, bias, bias};
#pragma unroll
        for (int kk = 0; kk < 4; kk++) c = MFMA(af[kk], Bow[(nt * 4 + kk) * 64 + lane], c);
        float w2 = ow2[nt * 16 + col];
#pragma unroll
        for (int reg = 0; reg < 4; reg++) p[reg] += sspf(c[reg]) * w2;
    }
#pragma unroll
    for (int reg = 0; reg < 4; reg++)
        R[(w * 16 + quad * 4 + reg) * 17 + col] = p[reg];
    __syncthreads();
    if (t < 64) {
        int n = n0 + t;
        float v = 0.f;
        int g = -1;
        if (n < N) {
            v = ob2[0];
#pragma unroll
            for (int c2 = 0; c2 < 16; c2++) v += R[t * 17 + c2];
            g = batch[n];
        }
#pragma unroll
        for (int off2 = 1; off2 < 64; off2 <<= 1) {
            float vv = __shfl_down(v, off2, 64);
            int gg = __shfl_down(g, off2, 64);
            if (lane + off2 < 64 && gg == g) v += vv;
        }
        int gp = __shfl_up(g, 1, 64);
        bool head = (lane == 0) || (g != gp);
        if (head && g >= 0) unsafeAtomicAdd(&out[g], v);
    }
}

// ---------------------------------------------------------------------------
extern "C" void kernel_launch(void* const* d_in, const int* in_sizes, int n_in,
                              void* d_out, int out_size, void* d_ws, size_t ws_size,
                              hipStream_t stream)
{
    const int*   z    = (const int*)d_in[0];
    const float* pos  = (const float*)d_in[1];
    const int*   batc = (const int*)d_in[2];
    const int*   ei   = (const int*)d_in[3];
    const float* emb  = (const float*)d_in[4];
    const float* mw1  = (const float*)d_in[5];
    const float* mb1  = (const float*)d_in[6];
    const float* mw2  = (const float*)d_in[7];
    const float* mb2  = (const float*)d_in[8];
    const float* l1w  = (const float*)d_in[9];
    const float* l2w  = (const float*)d_in[10];
    const float* l2b  = (const float*)d_in[11];
    const float* lw   = (const float*)d_in[12];
    const float* lb   = (const float*)d_in[13];
    const float* ow1  = (const float*)d_in[14];
    const float* ob1  = (const float*)d_in[15];
    const float* ow2  = (const float*)d_in[16];
    const float* ob2  = (const float*)d_in[17];
    float* out = (float*)d_out;

    int N = in_sizes[0];
    int E = in_sizes[3] / 2;
    int nb1 = (N + 127) >> 7;        // coarse buckets (<=512 for N<=65536)

    char* ws = (char*)d_ws;
    size_t off = 0;
    auto alloc = [&](size_t bytes) {
        void* p = ws + off;
        off = (off + bytes + 255) & ~(size_t)255;
        return p;
    };
    float* h      = (float*)alloc((size_t)N * HCH * 4);
    unsigned short* xjb = (unsigned short*)alloc((size_t)N * FCH * 2);
    float* agg    = (float*)alloc((size_t)N * FCH * 4);
    int2*  ebuf   = (int2*)alloc((size_t)nb1 * CAP1 * 8);
    int2*  edata  = (int2*)alloc((size_t)E * 8);
    unsigned short* Wtab = (unsigned short*)alloc((size_t)LN * TBL * 64 * 2);
    int*   gcur   = (int*)alloc((size_t)nb1 * 64);      // 1 cursor / 64B line
    short* l1wp   = (short*)alloc(LN * 8192 * 2);
    short* l2wp   = (short*)alloc(LN * 8192 * 2);
    short* lwp    = (short*)alloc(LN * 16384 * 2);
    short* ow1p   = (short*)alloc(8192 * 2);

    int NB = (N + 63) / 64;
    int EB256 = (E + 255) / 256;
    int S1B = (E + CHUNK - 1) / CHUNK;

    k_prep<<<32, 256, 0, stream>>>(l1w, l2w, lw, ow1, l1wp, l2wp, lwp, ow1p);
    k_wtab<<<LN * TBL, 64, 0, stream>>>(mw1, mb1, mw2, mb2, Wtab);
    hipMemsetAsync(gcur, 0, (size_t)nb1 * 64, stream);
    k_s1<<<S1B, 256, 0, stream>>>(ei, pos, gcur, ebuf, E, nb1);
    k_s2<<<nb1, 512, 0, stream>>>(ebuf, gcur, edata, nb1);
    hipMemsetAsync(out, 0, (size_t)out_size * sizeof(float), stream);

    k_node0<<<NB, 256, 0, stream>>>(z, emb, l1wp, h, xjb, agg, N);
    for (int l = 0; l < LN; l++) {
        k_edge<<<EB256, 256, 0, stream>>>(edata, xjb,
                                          Wtab + (size_t)l * TBL * 64, agg, E);
        if (l < LN - 1) {
            k_update<<<NB, 256, 0, stream>>>(agg, l2wp, l2b, lwp, lb,
                                             l1wp + (l + 1) * 8192, h, xjb, l, N);
        } else {
            k_final<<<NB, 256, 0, stream>>>(agg, l2wp, l2b, lwp, lb, ow1p,
                                            ob1, ow2, ob2, batc, h, out, l, N);
        }
    }
}

// Round 16
// 383.673 us; speedup vs baseline: 1.0730x; 1.0730x over previous
//
#include <hip/hip_runtime.h>

// ---------------------------------------------------------------------------
// SchNet-style GNN on MI355X — R16 (= R14, the best measured configuration).
// R15's carried-accumulator k_edge regressed (serial per-wave round chain +
// 4x fewer blocks -> latency exposed); reverted to R14's 4-parallel-wave
// structure. k_s1 frozen at its gather-latency floor (R12-R14).
// ---------------------------------------------------------------------------

typedef short bf16x8 __attribute__((ext_vector_type(8)));
typedef unsigned short ushort8 __attribute__((ext_vector_type(8)));
typedef float floatx4 __attribute__((ext_vector_type(4)));

#define HCH 128
#define FCH 64
#define GCH 50
#define LN  3
#define TBL 4096
#define CAP1 6144        // slots per 128-node coarse bucket (mean 4096)
#define CHUNK 1024       // edges per k_s1 block
#define DMAX 8.6603f     // pos in [0,5)^3 -> d <= 5*sqrt(3)

#define MFMA(a, b, c) __builtin_amdgcn_mfma_f32_16x16x32_bf16((a), (b), (c), 0, 0, 0)

__device__ __forceinline__ unsigned short f2bf(float x) {
    unsigned int u = __float_as_uint(x);
    unsigned int r = (u + 0x7FFFu + ((u >> 16) & 1u)) >> 16;
    return (unsigned short)r;
}

__device__ __forceinline__ unsigned pk2bf(float lo, float hi) {
    unsigned ulo = __float_as_uint(lo) + 0x8000u;
    unsigned uhi = __float_as_uint(hi) + 0x8000u;
    return __builtin_amdgcn_perm(uhi, ulo, 0x07060302u);
}

__device__ __forceinline__ float bf2f(unsigned short u) {
    return __uint_as_float((unsigned)u << 16);
}

__device__ __forceinline__ float sspf(float x) {
    float t = __expf(-fabsf(x));
    float l = __logf(1.f + t);
    return fmaxf(x, 0.f) + l - 0.69314718056f;
}

// ---------------------------------------------------------------------------
// frag fill for node-side MFMA weights (B-fragment order)
// ---------------------------------------------------------------------------
__device__ __forceinline__ void fill_frag(const float* __restrict__ src,
                                          short* __restrict__ dst,
                                          int K, int F, int Ksrc,
                                          int tid, int nthr)
{
    int kc = K >> 5;
    int total = (F >> 4) * kc * 512;
    for (int i = tid; i < total; i += nthr) {
        int j = i & 7;
        int lane = (i >> 3) & 63;
        int rest = i >> 9;
        int kk = rest % kc;
        int nt = rest / kc;
        int k = kk * 32 + ((lane >> 4) << 3) + j;
        int f = nt * 16 + (lane & 15);
        float v = (k < Ksrc) ? src[k * F + f] : 0.f;
        dst[i] = (short)f2bf(v);
    }
}

__global__ void k_prep(const float* __restrict__ l1w, const float* __restrict__ l2w,
                       const float* __restrict__ lw,  const float* __restrict__ ow1,
                       short* __restrict__ l1wp, short* __restrict__ l2wp,
                       short* __restrict__ lwp,  short* __restrict__ ow1p)
{
    int tid = blockIdx.x * blockDim.x + threadIdx.x;
    int nthr = gridDim.x * blockDim.x;
    for (int l = 0; l < LN; l++) {
        fill_frag(l1w + l * HCH * FCH, l1wp + l * 8192, 128, 64, 128, tid, nthr);
        fill_frag(l2w + l * FCH * HCH, l2wp + l * 8192, 64, 128, 64, tid, nthr);
        fill_frag(lw  + l * HCH * HCH, lwp  + l * 16384, 128, 128, 128, tid, nthr);
    }
    fill_frag(ow1, ow1p, 128, 64, 128, tid, nthr);
}

// ---------------------------------------------------------------------------
// Wtab[l][k][f] = (ssp(ea(d_k)@mw1+b1)@mw2+b2)[f] * C(d_k), bf16.
// ---------------------------------------------------------------------------
__global__ __launch_bounds__(64) void k_wtab(
    const float* __restrict__ mw1, const float* __restrict__ mb1,
    const float* __restrict__ mw2, const float* __restrict__ mb2,
    unsigned short* __restrict__ Wtb)
{
    __shared__ float sh[64];
    int blk = blockIdx.x;          // l*TBL + k
    int l = blk / TBL, k = blk - l * TBL;
    int f = threadIdx.x;
    float d = (float)k * (DMAX / (float)(TBL - 1));
    const float step = 10.f / 49.f;
    const float coeff = -0.5f / (step * step);

    float t1 = mb1[l * 64 + f];
    const float* w1 = mw1 + l * GCH * 64;
    for (int g = 0; g < GCH; g++) {
        float u = d - (float)g * step;
        t1 += __expf(coeff * u * u) * w1[g * 64 + f];
    }
    sh[f] = sspf(t1);              // one wave: program order suffices
    float acc = mb2[l * 64 + f];
    const float* w2 = mw2 + l * 64 * 64;
    for (int g = 0; g < 64; g++) acc += sh[g] * w2[g * 64 + f];
    float C = 0.5f * (__cosf(d * 0.31415926535897932f) + 1.f);
    Wtb[(size_t)blk * 64 + f] = f2bf(acc * C);
}

// ---------------------------------------------------------------------------
// Stage 1: coarse-bucket (dst>>7) partition of a 1024-edge chunk.
// (frozen — at its latency floor per R12-R14)
// ---------------------------------------------------------------------------
__global__ __launch_bounds__(256, 2) void k_s1(
    const int* __restrict__ ei, const float* __restrict__ pos,
    int* __restrict__ gcur, int2* __restrict__ ebuf, int E, int nb1)
{
    __shared__ int hist[512];
    __shared__ int lstart[512];
    __shared__ int lcur[512];
    __shared__ int gbase[512];
    __shared__ int wsum[4];
    __shared__ int2 stage[CHUNK];

    int t = threadIdx.x, lane = t & 63, w = t >> 6;
    int e0 = blockIdx.x * CHUNK;
    int e1 = min(e0 + CHUNK, E);
    int cnt = e1 - e0;

    for (int i = t; i < 512; i += 256) hist[i] = 0;
    __syncthreads();

    int esrc[4], edst[4];
    float psx[4], psy[4], psz[4], pdx[4], pdy[4], pdz[4];
    bool val[4];
#pragma unroll
    for (int i = 0; i < 4; i++) {
        int e = e0 + t + i * 256;
        val[i] = e < e1;
        int ec = min(e, E - 1);
        esrc[i] = ei[ec];
        edst[i] = ei[E + ec];
    }
#pragma unroll
    for (int i = 0; i < 4; i++) {
        int s = esrc[i], d2 = edst[i];
        psx[i] = pos[s * 3 + 0]; psy[i] = pos[s * 3 + 1]; psz[i] = pos[s * 3 + 2];
        pdx[i] = pos[d2 * 3 + 0]; pdy[i] = pos[d2 * 3 + 1]; pdz[i] = pos[d2 * 3 + 2];
    }
    int2 my[4];
    int  mybk[4];
#pragma unroll
    for (int i = 0; i < 4; i++) {
        float dx = psx[i] - pdx[i];
        float dy = psy[i] - pdy[i];
        float dz = psz[i] - pdz[i];
        float dist = sqrtf(dx * dx + dy * dy + dz * dz);
        int tix = (int)(dist * ((float)(TBL - 1) / DMAX) + 0.5f);
        tix = (tix > TBL - 1) ? (TBL - 1) : tix;
        my[i] = make_int2(esrc[i] | (tix << 17), edst[i]);
        mybk[i] = val[i] ? (edst[i] >> 7) : -1;
        if (mybk[i] >= 0) atomicAdd(&hist[mybk[i]], 1);
    }
    __syncthreads();

    {
        int base = w * 128;
        int c0 = hist[base + lane];
        int c1 = hist[base + 64 + lane];
        int a = c0, b = c1;
#pragma unroll
        for (int o = 1; o < 64; o <<= 1) {
            int ua = __shfl_up(a, o, 64);
            int ub = __shfl_up(b, o, 64);
            if (lane >= o) { a += ua; b += ub; }
        }
        int atot = __shfl(a, 63, 64);
        b += atot;
        if (lane == 63) wsum[w] = b;
        __syncthreads();
        int prefix = 0;
#pragma unroll
        for (int i = 0; i < 4; i++) if (i < w) prefix += wsum[i];
        int ls0 = prefix + a - c0;
        int ls1 = prefix + b - c1;
        int bk0 = base + lane, bk1 = base + 64 + lane;
        lstart[bk0] = ls0; lcur[bk0] = ls0;
        lstart[bk1] = ls1; lcur[bk1] = ls1;
        int base0 = (c0 && bk0 < nb1) ? atomicAdd(&gcur[bk0 * 16], c0) : 0;
        int base1 = (c1 && bk1 < nb1) ? atomicAdd(&gcur[bk1 * 16], c1) : 0;
        gbase[bk0] = bk0 * CAP1 + base0;
        gbase[bk1] = bk1 * CAP1 + base1;
    }
    __syncthreads();

#pragma unroll
    for (int i = 0; i < 4; i++) {
        if (mybk[i] >= 0) {
            int ofs = atomicAdd(&lcur[mybk[i]], 1);
            stage[ofs] = my[i];
        }
    }
    __syncthreads();

    for (int i = t; i < cnt; i += 256) {
        int2 ed = stage[i];
        int bk = ed.y >> 7;
        int g = gbase[bk] + (i - lstart[bk]);
        if (g < bk * CAP1 + CAP1) ebuf[g] = ed;
    }
}

// ---------------------------------------------------------------------------
// Stage 2: per-bucket LDS counting sort by dst -> dense sorted int2 edata.
// Computes its own global prefix (reduction over gcur).
// ---------------------------------------------------------------------------
__global__ __launch_bounds__(512) void k_s2(
    const int2* __restrict__ ebuf, const int* __restrict__ gcur,
    int2* __restrict__ edata, int nb1)
{
    __shared__ int hist[128];
    __shared__ int bcur[128];
    __shared__ int wred[8];
    int t = threadIdx.x, lane = t & 63, w = t >> 6, bk = blockIdx.x;
    int cnt = min(gcur[bk * 16], CAP1);

    int v = (t < bk && t < nb1) ? min(gcur[t * 16], CAP1) : 0;
#pragma unroll
    for (int o = 32; o; o >>= 1) v += __shfl_down(v, o, 64);
    if (lane == 0) wred[w] = v;
    if (t < 128) hist[t] = 0;
    __syncthreads();
    int gs = 0;
#pragma unroll
    for (int i = 0; i < 8; i++) gs += wred[i];

    const int2* eb = ebuf + (size_t)bk * CAP1;
    for (int i = t; i < cnt; i += 512)
        atomicAdd(&hist[eb[i].y & 127], 1);
    __syncthreads();
    int myc = (t < 128) ? hist[t] : 0;
    for (int o = 1; o < 128; o <<= 1) {
        int u = (t < 128 && t >= o) ? hist[t - o] : 0;
        __syncthreads();
        if (t < 128) hist[t] += u;
        __syncthreads();
    }
    if (t < 128) bcur[t] = gs + hist[t] - myc;
    __syncthreads();
    for (int i = t; i < cnt; i += 512) {
        int2 ed = eb[i];
        int dl = ed.y & 127;
        int p = atomicAdd(&bcur[dl], 1);
        edata[p] = ed;
    }
}

// ---------------------------------------------------------------------------
// k_node0: h = emb[z]; xj = h @ l1w[0] (bf16 out); agg = 0 for layer 0
// ---------------------------------------------------------------------------
__global__ __launch_bounds__(256) void k_node0(const int* __restrict__ z,
    const float* __restrict__ emb, const short* __restrict__ l1wp0,
    float* __restrict__ h, unsigned short* __restrict__ xjb,
    float* __restrict__ agg, int N)
{
    __shared__ __align__(16) short A3[8192];
    __shared__ int zL[64];
    int t = threadIdx.x, lane = t & 63, w = t >> 6;
    int n0 = blockIdx.x * 64;
    if (t < 64) { int n = n0 + t; zL[t] = (n < N) ? z[n] : 0; }
    __syncthreads();
    for (int i = t; i < 4096; i += 256) {
        int n = n0 + (i >> 6);
        if (n < N) agg[(size_t)n * FCH + (i & 63)] = 0.f;
    }
#pragma unroll
    for (int m = 0; m < 16; m++) {
        int ii = lane + 64 * m;
        int rloc = ii >> 6;
        int k0 = (ii & 63) * 2;
        int n = n0 + w * 16 + rloc;
        float2 v = make_float2(0.f, 0.f);
        if (n < N) {
            v = *(const float2*)(&emb[(size_t)zL[w * 16 + rloc] * HCH + k0]);
            *(float2*)(&h[(size_t)n * HCH + k0]) = v;
        }
        unsigned pk = pk2bf(v.x, v.y);
        int si = w * 2048 + (k0 >> 5) * 512 + (rloc + 16 * ((k0 >> 3) & 3)) * 8 + (k0 & 7);
        *(unsigned*)(&A3[si]) = pk;
    }
    int quad = lane >> 4, col = lane & 15;
    const bf16x8* B = (const bf16x8*)l1wp0;
    bf16x8 af[4];
#pragma unroll
    for (int kk = 0; kk < 4; kk++)
        af[kk] = *(const bf16x8*)(&A3[w * 2048 + kk * 512 + lane * 8]);
#pragma unroll
    for (int nt = 0; nt < 4; nt++) {
        floatx4 c = {0.f, 0.f, 0.f, 0.f};
#pragma unroll
        for (int kk = 0; kk < 4; kk++) c = MFMA(af[kk], B[(nt * 4 + kk) * 64 + lane], c);
        int f = nt * 16 + col;
#pragma unroll
        for (int reg = 0; reg < 4; reg++) {
            int n = n0 + w * 16 + quad * 4 + reg;
            if (n < N) xjb[(size_t)n * FCH + f] = f2bf(c[reg]);
        }
    }
}

// ---------------------------------------------------------------------------
// Edge kernel (R14 structure): 64 sorted edges/block, 4 thr/edge, bf16 xj,
// no barriers; intra-wave segmented reduce + boundary global atomics.
// ---------------------------------------------------------------------------
__global__ __launch_bounds__(256) void k_edge(
    const int2* __restrict__ edata, const unsigned short* __restrict__ xjb,
    const unsigned short* __restrict__ Wt, float* __restrict__ agg, int E)
{
    __shared__ float M[64 * 68];
    __shared__ int tD[64];

    int t = threadIdx.x, lane = t & 63, w = t >> 6;
    int r  = w * 16 + (lane >> 2);
    int fq = lane & 3;
    int eg = blockIdx.x * 64 + r;

    int2 ed = make_int2(0, -1);
    if (eg < E) ed = edata[eg];
    int src = ed.x & 0x1FFFF;
    int tix = ((unsigned)ed.x) >> 17;
    if (fq == 0) tD[r] = ed.y;

    const ushort8* Wr = (const ushort8*)(Wt + ((size_t)tix << 6) + fq * 16);
    const ushort8* X  = (const ushort8*)(xjb + ((size_t)src << 6) + fq * 16);
    ushort8 w0 = Wr[0];
    ushort8 w1 = Wr[1];
    ushort8 xA = X[0];
    ushort8 xB = X[1];

    float* Mr = &M[r * 68 + fq * 16];
    float4 m;
    m.x = bf2f(w0[0]) * bf2f(xA[0]); m.y = bf2f(w0[1]) * bf2f(xA[1]);
    m.z = bf2f(w0[2]) * bf2f(xA[2]); m.w = bf2f(w0[3]) * bf2f(xA[3]);
    *(float4*)(Mr + 0) = m;
    m.x = bf2f(w0[4]) * bf2f(xA[4]); m.y = bf2f(w0[5]) * bf2f(xA[5]);
    m.z = bf2f(w0[6]) * bf2f(xA[6]); m.w = bf2f(w0[7]) * bf2f(xA[7]);
    *(float4*)(Mr + 4) = m;
    m.x = bf2f(w1[0]) * bf2f(xB[0]); m.y = bf2f(w1[1]) * bf2f(xB[1]);
    m.z = bf2f(w1[2]) * bf2f(xB[2]); m.w = bf2f(w1[3]) * bf2f(xB[3]);
    *(float4*)(Mr + 8) = m;
    m.x = bf2f(w1[4]) * bf2f(xB[4]); m.y = bf2f(w1[5]) * bf2f(xB[5]);
    m.z = bf2f(w1[6]) * bf2f(xB[6]); m.w = bf2f(w1[7]) * bf2f(xB[7]);
    *(float4*)(Mr + 12) = m;

    {
        int f = lane;
        int base = w * 16;
        float a = 0.f;
        int cur = tD[base];
#pragma unroll
        for (int i = 0; i < 16; i++) {
            int d2 = tD[base + i];
            if (d2 != cur) {
                if (cur >= 0) unsafeAtomicAdd(&agg[(size_t)cur * FCH + f], a);
                a = 0.f; cur = d2;
            }
            a += M[(base + i) * 68 + f];
        }
        if (cur >= 0) unsafeAtomicAdd(&agg[(size_t)cur * FCH + f], a);
    }
}

// ---------------------------------------------------------------------------
// Node update (layers 0,1): single LDS arena; zeroes its agg rows for the
// next layer right after staging them.
// ---------------------------------------------------------------------------
__global__ __launch_bounds__(256) void k_update(
    float* __restrict__ agg, const short* __restrict__ l2wp,
    const float* __restrict__ l2b, const short* __restrict__ lwp,
    const float* __restrict__ lb,  const short* __restrict__ l1wp_next,
    float* __restrict__ h, unsigned short* __restrict__ xjb, int layer, int N)
{
    __shared__ __align__(16) short AR[8192];
    int t = threadIdx.x, lane = t & 63, w = t >> 6;
    int n0 = blockIdx.x * 64;
    short* WR = &AR[w * 2048];
#pragma unroll
    for (int m = 0; m < 8; m++) {
        int ii = lane + 64 * m;
        int rloc = ii >> 5;
        int k0 = (ii & 31) * 2;
        int n = n0 + w * 16 + rloc;
        float2 v = make_float2(0.f, 0.f);
        if (n < N) v = *(const float2*)(&agg[(size_t)n * FCH + k0]);
        unsigned pk = pk2bf(v.x, v.y);
        int si = (k0 >> 5) * 512 + (rloc + 16 * ((k0 >> 3) & 3)) * 8 + (k0 & 7);
        *(unsigned*)(&WR[si]) = pk;
    }
#pragma unroll
    for (int i = 0; i < 16; i++) {
        int n = n0 + w * 16 + i;
        if (n < N) agg[(size_t)n * FCH + lane] = 0.f;
    }
    int quad = lane >> 4, col = lane & 15;
    const bf16x8* Bl2 = (const bf16x8*)(l2wp + layer * 8192);
    const bf16x8* Blw = (const bf16x8*)(lwp + layer * 16384);
    const bf16x8* Bl1 = (const bf16x8*)l1wp_next;

    bf16x8 a0 = *(const bf16x8*)(&WR[lane * 8]);
    bf16x8 a1 = *(const bf16x8*)(&WR[512 + lane * 8]);
#pragma unroll
    for (int nt = 0; nt < 8; nt++) {
        float bias = l2b[layer * HCH + nt * 16 + col];
        floatx4 c = {bias, bias, bias, bias};
        c = MFMA(a0, Bl2[(nt * 2 + 0) * 64 + lane], c);
        c = MFMA(a1, Bl2[(nt * 2 + 1) * 64 + lane], c);
        int f = nt * 16 + col;
        int si0 = (f >> 5) * 512 + (16 * ((f >> 3) & 3)) * 8 + (f & 7);
#pragma unroll
        for (int reg = 0; reg < 4; reg++)
            WR[si0 + (quad * 4 + reg) * 8] = (short)f2bf(sspf(c[reg]));
    }
    bf16x8 af[4];
#pragma unroll
    for (int kk = 0; kk < 4; kk++)
        af[kk] = *(const bf16x8*)(&WR[kk * 512 + lane * 8]);
#pragma unroll
    for (int nt = 0; nt < 8; nt++) {
        float bias = lb[layer * HCH + nt * 16 + col];
        floatx4 c = {bias, bias, bias, bias};
#pragma unroll
        for (int kk = 0; kk < 4; kk++) c = MFMA(af[kk], Blw[(nt * 4 + kk) * 64 + lane], c);
        int f = nt * 16 + col;
        int si0 = (f >> 5) * 512 + (16 * ((f >> 3) & 3)) * 8 + (f & 7);
#pragma unroll
        for (int reg = 0; reg < 4; reg++) {
            int n = n0 + w * 16 + quad * 4 + reg;
            float hv = 0.f;
            if (n < N) {
                hv = h[(size_t)n * HCH + f] + c[reg];
                h[(size_t)n * HCH + f] = hv;
            }
            WR[si0 + (quad * 4 + reg) * 8] = (short)f2bf(hv);
        }
    }
#pragma unroll
    for (int kk = 0; kk < 4; kk++)
        af[kk] = *(const bf16x8*)(&WR[kk * 512 + lane * 8]);
#pragma unroll
    for (int nt = 0; nt < 4; nt++) {
        floatx4 c = {0.f, 0.f, 0.f, 0.f};
#pragma unroll
        for (int kk = 0; kk < 4; kk++) c = MFMA(af[kk], Bl1[(nt * 4 + kk) * 64 + lane], c);
        int f = nt * 16 + col;
#pragma unroll
        for (int reg = 0; reg < 4; reg++) {
            int n = n0 + w * 16 + quad * 4 + reg;
            if (n < N) xjb[(size_t)n * FCH + f] = f2bf(c[reg]);
        }
    }
}

// ---------------------------------------------------------------------------
// Final layer: node update + output MLP + segmented-shuffle readout.
// ---------------------------------------------------------------------------
__global__ __launch_bounds__(256) void k_final(
    const float* __restrict__ agg, const short* __restrict__ l2wp,
    const float* __restrict__ l2b, const short* __restrict__ lwp,
    const float* __restrict__ lb,  const short* __restrict__ ow1p,
    const float* __restrict__ ob1, const float* __restrict__ ow2,
    const float* __restrict__ ob2, const int* __restrict__ batch,
    const float* __restrict__ h, float* __restrict__ out, int layer, int N)
{
    __shared__ __align__(16) short AR[8192];
    __shared__ float R[64 * 17];
    int t = threadIdx.x, lane = t & 63, w = t >> 6;
    int n0 = blockIdx.x * 64;
    short* WR = &AR[w * 2048];
#pragma unroll
    for (int m = 0; m < 8; m++) {
        int ii = lane + 64 * m;
        int rloc = ii >> 5;
        int k0 = (ii & 31) * 2;
        int n = n0 + w * 16 + rloc;
        float2 v = make_float2(0.f, 0.f);
        if (n < N) v = *(const float2*)(&agg[(size_t)n * FCH + k0]);
        unsigned pk = pk2bf(v.x, v.y);
        int si = (k0 >> 5) * 512 + (rloc + 16 * ((k0 >> 3) & 3)) * 8 + (k0 & 7);
        *(unsigned*)(&WR[si]) = pk;
    }
    int quad = lane >> 4, col = lane & 15;
    const bf16x8* Bl2 = (const bf16x8*)(l2wp + layer * 8192);
    const bf16x8* Blw = (const bf16x8*)(lwp + layer * 16384);
    const bf16x8* Bow = (const bf16x8*)ow1p;

    bf16x8 a0 = *(const bf16x8*)(&WR[lane * 8]);
    bf16x8 a1 = *(const bf16x8*)(&WR[512 + lane * 8]);
#pragma unroll
    for (int nt = 0; nt < 8; nt++) {
        float bias = l2b[layer * HCH + nt * 16 + col];
        floatx4 c = {bias, bias, bias, bias};
        c = MFMA(a0, Bl2[(nt * 2 + 0) * 64 + lane], c);
        c = MFMA(a1, Bl2[(nt * 2 + 1) * 64 + lane], c);
        int f = nt * 16 + col;
        int si0 = (f >> 5) * 512 + (16 * ((f >> 3) & 3)) * 8 + (f & 7);
#pragma unroll
        for (int reg = 0; reg < 4; reg++)
            WR[si0 + (quad * 4 + reg) * 8] = (short)f2bf(sspf(c[reg]));
    }
    bf16x8 af[4];
#pragma unroll
    for (int kk = 0; kk < 4; kk++)
        af[kk] = *(const bf16x8*)(&WR[kk * 512 + lane * 8]);
#pragma unroll
    for (int nt = 0; nt < 8; nt++) {
        float bias = lb[layer * HCH + nt * 16 + col];
        floatx4 c = {bias, bias, bias, bias};
#pragma unroll
        for (int kk = 0; kk < 4; kk++) c = MFMA(af[kk], Blw[(nt * 4 + kk) * 64 + lane], c);
        int f = nt * 16 + col;
        int si0 = (f >> 5) * 512 + (16 * ((f >> 3) & 3)) * 8 + (f & 7);
#pragma unroll
        for (int reg = 0; reg < 4; reg++) {
            int n = n0 + w * 16 + quad * 4 + reg;
            float hv = 0.f;
            if (n < N) hv = h[(size_t)n * HCH + f] + c[reg];
            WR[si0 + (quad * 4 + reg) * 8] = (short)f2bf(hv);
        }
    }
#pragma unroll
    for (int kk = 0; kk < 4; kk++)
        af[kk] = *(const bf16x8*)(&WR[kk * 512 + lane * 8]);
    float p[4] = {0.f, 0.f, 0.f, 0.f};
#pragma unroll
    for (int nt = 0; nt < 4; nt++) {
        float bias = ob1[nt * 16 + col];
        floatx4 c = {bias, bias, bias, bias};
#pragma unroll
        for (int kk = 0; kk < 4; kk++) c = MFMA(af[kk], Bow[(nt * 4 + kk) * 64 + lane], c);
        float w2 = ow2[nt * 16 + col];
#pragma unroll
        for (int reg = 0; reg < 4; reg++) p[reg] += sspf(c[reg]) * w2;
    }
#pragma unroll
    for (int reg = 0; reg < 4; reg++)
        R[(w * 16 + quad * 4 + reg) * 17 + col] = p[reg];
    __syncthreads();
    if (t < 64) {
        int n = n0 + t;
        float v = 0.f;
        int g = -1;
        if (n < N) {
            v = ob2[0];
#pragma unroll
            for (int c2 = 0; c2 < 16; c2++) v += R[t * 17 + c2];
            g = batch[n];
        }
#pragma unroll
        for (int off2 = 1; off2 < 64; off2 <<= 1) {
            float vv = __shfl_down(v, off2, 64);
            int gg = __shfl_down(g, off2, 64);
            if (lane + off2 < 64 && gg == g) v += vv;
        }
        int gp = __shfl_up(g, 1, 64);
        bool head = (lane == 0) || (g != gp);
        if (head && g >= 0) unsafeAtomicAdd(&out[g], v);
    }
}

// ---------------------------------------------------------------------------
extern "C" void kernel_launch(void* const* d_in, const int* in_sizes, int n_in,
                              void* d_out, int out_size, void* d_ws, size_t ws_size,
                              hipStream_t stream)
{
    const int*   z    = (const int*)d_in[0];
    const float* pos  = (const float*)d_in[1];
    const int*   batc = (const int*)d_in[2];
    const int*   ei   = (const int*)d_in[3];
    const float* emb  = (const float*)d_in[4];
    const float* mw1  = (const float*)d_in[5];
    const float* mb1  = (const float*)d_in[6];
    const float* mw2  = (const float*)d_in[7];
    const float* mb2  = (const float*)d_in[8];
    const float* l1w  = (const float*)d_in[9];
    const float* l2w  = (const float*)d_in[10];
    const float* l2b  = (const float*)d_in[11];
    const float* lw   = (const float*)d_in[12];
    const float* lb   = (const float*)d_in[13];
    const float* ow1  = (const float*)d_in[14];
    const float* ob1  = (const float*)d_in[15];
    const float* ow2  = (const float*)d_in[16];
    const float* ob2  = (const float*)d_in[17];
    float* out = (float*)d_out;

    int N = in_sizes[0];
    int E = in_sizes[3] / 2;
    int nb1 = (N + 127) >> 7;        // coarse buckets (<=512 for N<=65536)

    char* ws = (char*)d_ws;
    size_t off = 0;
    auto alloc = [&](size_t bytes) {
        void* p = ws + off;
        off = (off + bytes + 255) & ~(size_t)255;
        return p;
    };
    float* h      = (float*)alloc((size_t)N * HCH * 4);
    unsigned short* xjb = (unsigned short*)alloc((size_t)N * FCH * 2);
    float* agg    = (float*)alloc((size_t)N * FCH * 4);
    int2*  ebuf   = (int2*)alloc((size_t)nb1 * CAP1 * 8);
    int2*  edata  = (int2*)alloc((size_t)E * 8);
    unsigned short* Wtab = (unsigned short*)alloc((size_t)LN * TBL * 64 * 2);
    int*   gcur   = (int*)alloc((size_t)nb1 * 64);      // 1 cursor / 64B line
    short* l1wp   = (short*)alloc(LN * 8192 * 2);
    short* l2wp   = (short*)alloc(LN * 8192 * 2);
    short* lwp    = (short*)alloc(LN * 16384 * 2);
    short* ow1p   = (short*)alloc(8192 * 2);

    int NB = (N + 63) / 64;
    int EB = (E + 63) / 64;
    int S1B = (E + CHUNK - 1) / CHUNK;

    k_prep<<<32, 256, 0, stream>>>(l1w, l2w, lw, ow1, l1wp, l2wp, lwp, ow1p);
    k_wtab<<<LN * TBL, 64, 0, stream>>>(mw1, mb1, mw2, mb2, Wtab);
    hipMemsetAsync(gcur, 0, (size_t)nb1 * 64, stream);
    k_s1<<<S1B, 256, 0, stream>>>(ei, pos, gcur, ebuf, E, nb1);
    k_s2<<<nb1, 512, 0, stream>>>(ebuf, gcur, edata, nb1);
    hipMemsetAsync(out, 0, (size_t)out_size * sizeof(float), stream);

    k_node0<<<NB, 256, 0, stream>>>(z, emb, l1wp, h, xjb, agg, N);
    for (int l = 0; l < LN; l++) {
        k_edge<<<EB, 256, 0, stream>>>(edata, xjb,
                                       Wtab + (size_t)l * TBL * 64, agg, E);
        if (l < LN - 1) {
            k_update<<<NB, 256, 0, stream>>>(agg, l2wp, l2b, lwp, lb,
                                             l1wp + (l + 1) * 8192, h, xjb, l, N);
        } else {
            k_final<<<NB, 256, 0, stream>>>(agg, l2wp, l2b, lwp, lb, ow1p,
                                            ob1, ow2, ob2, batc, h, out, l, N);
        }
    }
}